// Round 11
// baseline (902.298 us; speedup 1.0000x reference)
//
#include <hip/hip_runtime.h>
#include <hip/hip_bf16.h>
#include <math.h>

#define NN   50000
#define INF_ 64
#define HH   128
#define NSH  8
#define TT   8
#define EE   400000
#define CC   10
#define MAXD 512

typedef __attribute__((ext_vector_type(8))) short short8;
typedef __attribute__((ext_vector_type(4))) short short4v;
typedef __attribute__((ext_vector_type(4))) float f32x4;

__device__ __forceinline__ float b2f(unsigned short u){
    unsigned v = ((unsigned)u) << 16; float f; __builtin_memcpy(&f, &v, 4); return f;
}
__device__ __forceinline__ unsigned short f2b(float f){
    unsigned x; __builtin_memcpy(&x, &f, 4);
    x += 0x7fffu + ((x >> 16) & 1u);
    return (unsigned short)(x >> 16);
}

// ---- weight preconvert ------------------------------------------------------
__global__ __launch_bounds__(256) void k_wcvt(const float* __restrict__ Wqkv,
    const float* __restrict__ Wo, const float* __restrict__ Wp,
    const float* __restrict__ Wg, unsigned short* __restrict__ wkv,
    unsigned short* __restrict__ wq, unsigned short* __restrict__ wo_,
    unsigned short* __restrict__ wp_, unsigned short* __restrict__ wg_)
{
    int idx = blockIdx.x * 256 + threadIdx.x;
    if (idx < 32768) {                                  // K,V rows
        int r = idx >> 7, c = idx & 127;
        int hh = r >> 6, rem = r & 63;                  // rem<32: k, else v
        wkv[idx] = f2b(Wqkv[(hh * 96 + 32 + rem) * HH + c]);
    } else if (idx < 49152) {                           // Q rows
        int i2 = idx - 32768;
        int r = i2 >> 7, c = i2 & 127;
        int hh = r >> 5, dd = r & 31;
        wq[i2] = f2b(Wqkv[(hh * 96 + dd) * HH + c]);
    } else if (idx < 65536) {
        int i2 = idx - 49152;
        wo_[i2] = f2b(Wo[i2]);
    } else if (idx < 73728) {
        int i2 = idx - 65536;
        wp_[i2] = f2b(Wp[i2]);
    } else {                                            // < 90112
        int i2 = idx - 73728;
        wg_[i2] = f2b(Wg[i2]);
    }
}

// ---- fused: x = elu(x0@Wp.T+bp) (bf16); h = x@Wg.T (bf16); p1,p2 -----------
__global__ __launch_bounds__(256) void k_projh(const float* __restrict__ xo,
    const unsigned short* __restrict__ wp, const float* __restrict__ bp,
    const unsigned short* __restrict__ wg, const float* __restrict__ a,
    unsigned short* __restrict__ xb, unsigned short* __restrict__ h,
    float* __restrict__ p1, float* __restrict__ p2)
{
    __shared__ __align__(16) char lds[40960];
    int tid = threadIdx.x;
    int n0 = blockIdx.x * 64;
    int wid = tid >> 6, lane = tid & 63, lm = lane & 15, kg = lane >> 4;

    for (int w = tid; w < 512; w += 256) {
        int row = w >> 3, u = w & 7;
        int nr = n0 + row; if (nr >= NN) nr = NN - 1;
        const float4* src = (const float4*)(xo + (size_t)nr * INF_ + u * 8);
        float4 v0 = src[0], v1 = src[1];
        short8 p;
        p[0] = (short)f2b(v0.x); p[1] = (short)f2b(v0.y);
        p[2] = (short)f2b(v0.z); p[3] = (short)f2b(v0.w);
        p[4] = (short)f2b(v1.x); p[5] = (short)f2b(v1.y);
        p[6] = (short)f2b(v1.z); p[7] = (short)f2b(v1.w);
        *(short8*)(lds + ((row * 128 + u * 16) ^ ((row & 7) << 4))) = p;
    }
    __syncthreads();

    short8 bf1[2][2];
    #pragma unroll
    for (int ntl = 0; ntl < 2; ++ntl)
        #pragma unroll
        for (int ks = 0; ks < 2; ++ks)
            bf1[ntl][ks] = *(const short8*)(wp + (size_t)(wid * 32 + ntl * 16 + lm) * INF_ + ks * 32 + kg * 8);
    f32x4 acc1[4][2];
    #pragma unroll
    for (int mt = 0; mt < 4; ++mt)
        #pragma unroll
        for (int ntl = 0; ntl < 2; ++ntl)
            acc1[mt][ntl] = (f32x4){0.f, 0.f, 0.f, 0.f};
    #pragma unroll
    for (int mt = 0; mt < 4; ++mt) {
        int row = mt * 16 + lm, swz = (row & 7) << 4, ab = row * 128;
        short8 af[2];
        #pragma unroll
        for (int ks = 0; ks < 2; ++ks)
            af[ks] = *(short8*)(lds + ((ab + ks * 64 + kg * 16) ^ swz));
        #pragma unroll
        for (int ntl = 0; ntl < 2; ++ntl)
            #pragma unroll
            for (int ks = 0; ks < 2; ++ks)
                acc1[mt][ntl] = __builtin_amdgcn_mfma_f32_16x16x32_bf16(
                    af[ks], bf1[ntl][ks], acc1[mt][ntl], 0, 0, 0);
    }

    #pragma unroll
    for (int mt = 0; mt < 4; ++mt)
        #pragma unroll
        for (int ntl = 0; ntl < 2; ++ntl) {
            int j = wid * 32 + ntl * 16 + lm;
            float bpj = bp[j];
            #pragma unroll
            for (int r = 0; r < 4; ++r) {
                int rowl = mt * 16 + kg * 4 + r;
                float v = acc1[mt][ntl][r] + bpj;
                v = v > 0.f ? v : (__expf(v) - 1.f);
                int node = n0 + rowl;
                unsigned short vb = f2b(v);
                if (node < NN) xb[(size_t)node * HH + j] = vb;
                *(unsigned short*)(lds + 8192 + ((rowl * 256 + j * 2) ^ ((rowl & 7) << 4))) = vb;
            }
        }
    __syncthreads();

    short8 bf2[2][4];
    #pragma unroll
    for (int ntl = 0; ntl < 2; ++ntl)
        #pragma unroll
        for (int ks = 0; ks < 4; ++ks)
            bf2[ntl][ks] = *(const short8*)(wg + (size_t)(wid * 32 + ntl * 16 + lm) * HH + ks * 32 + kg * 8);
    f32x4 acc2[4][2];
    #pragma unroll
    for (int mt = 0; mt < 4; ++mt)
        #pragma unroll
        for (int ntl = 0; ntl < 2; ++ntl)
            acc2[mt][ntl] = (f32x4){0.f, 0.f, 0.f, 0.f};
    #pragma unroll
    for (int mt = 0; mt < 4; ++mt) {
        int row = mt * 16 + lm, swz = (row & 7) << 4, ab = row * 256;
        short8 af[4];
        #pragma unroll
        for (int ks = 0; ks < 4; ++ks)
            af[ks] = *(short8*)(lds + 8192 + ((ab + ks * 64 + kg * 16) ^ swz));
        #pragma unroll
        for (int ntl = 0; ntl < 2; ++ntl)
            #pragma unroll
            for (int ks = 0; ks < 4; ++ks)
                acc2[mt][ntl] = __builtin_amdgcn_mfma_f32_16x16x32_bf16(
                    af[ks], bf2[ntl][ks], acc2[mt][ntl], 0, 0, 0);
    }

    float a1v = a[lm], a2v = a[16 + lm];
    #pragma unroll
    for (int mt = 0; mt < 4; ++mt)
        #pragma unroll
        for (int ntl = 0; ntl < 2; ++ntl) {
            int head = wid * 2 + ntl;
            int j = wid * 32 + ntl * 16 + lm;
            float c1r[4], c2r[4];
            #pragma unroll
            for (int r = 0; r < 4; ++r) {
                float hv = acc2[mt][ntl][r];
                int node = n0 + mt * 16 + kg * 4 + r;
                if (node < NN) h[(size_t)node * HH + j] = f2b(hv);
                c1r[r] = hv * a1v;
                c2r[r] = hv * a2v;
            }
            #pragma unroll
            for (int off = 1; off < 16; off <<= 1)
                #pragma unroll
                for (int r = 0; r < 4; ++r) {
                    c1r[r] += __shfl_xor(c1r[r], off);
                    c2r[r] += __shfl_xor(c2r[r], off);
                }
            if (lm == 0) {
                #pragma unroll
                for (int r = 0; r < 4; ++r) {
                    int node = n0 + mt * 16 + kg * 4 + r;
                    if (node < NN) {
                        p1[(size_t)node * NSH + head] = c1r[r];
                        p2[(size_t)node * NSH + head] = c2r[r];
                    }
                }
            }
        }
}

// ---- degree histogram over all snapshots -----------------------------------
__global__ __launch_bounds__(256) void k_deg(const int* __restrict__ ei, int* __restrict__ deg)
{
    int e = blockIdx.x * 256 + threadIdx.x;
    int t = blockIdx.y;
    if (e >= EE) return;
    int dst = ei[(size_t)t * 2 * EE + EE + e];
    atomicAdd(&deg[t * NN + dst], 1);
}

// ---- hierarchical scan: chunk sums -> chunk offsets -> in-chunk scan --------
#define NCH 49   // ceil(50000/1024)

__global__ __launch_bounds__(256) void k_scan1(const int* __restrict__ deg,
    int* __restrict__ csum)
{
    int t = blockIdx.y, c = blockIdx.x, tid = threadIdx.x;
    int base = c * 1024;
    int s = 0;
    #pragma unroll
    for (int k = 0; k < 4; ++k) {
        int i = base + k * 256 + tid;
        if (i < NN) s += deg[t * NN + i];
    }
    #pragma unroll
    for (int off = 32; off; off >>= 1) s += __shfl_xor(s, off);
    __shared__ int sm[4];
    if ((tid & 63) == 0) sm[tid >> 6] = s;
    __syncthreads();
    if (tid == 0) csum[t * NCH + c] = sm[0] + sm[1] + sm[2] + sm[3];
}

__global__ __launch_bounds__(64) void k_scan2(int* __restrict__ csum)
{
    int t = threadIdx.x;
    if (t >= TT) return;
    int run = 0;
    for (int c = 0; c < NCH; ++c) {
        int v = csum[t * NCH + c];
        csum[t * NCH + c] = run;
        run += v;
    }
}

__global__ __launch_bounds__(256) void k_scan3(const int* __restrict__ deg,
    const int* __restrict__ csum, int* __restrict__ rowptr, int* __restrict__ cur)
{
    int t = blockIdx.y, c = blockIdx.x, tid = threadIdx.x;
    int i0 = c * 1024 + tid * 4;
    int d[4];
    int s = 0;
    #pragma unroll
    for (int k = 0; k < 4; ++k) {
        d[k] = (i0 + k < NN) ? deg[t * NN + i0 + k] : 0;
        s += d[k];
    }
    __shared__ int sm[256];
    sm[tid] = s;
    __syncthreads();
    for (int off = 1; off < 256; off <<= 1) {
        int v = (tid >= off) ? sm[tid - off] : 0;
        __syncthreads();
        sm[tid] += v;
        __syncthreads();
    }
    int run = csum[t * NCH + c] + sm[tid] - s;
    #pragma unroll
    for (int k = 0; k < 4; ++k) {
        int i = i0 + k;
        if (i < NN) {
            rowptr[t * NN + i] = run;
            cur[t * NN + i] = run;
            run += d[k];
        }
    }
}

// ---- scatter: dst-sort edge src ids (all t); intra-segment order is
//      nondeterministic (atomic cursor) — k_gat_node canonicalizes it --------
__global__ __launch_bounds__(256) void k_scatter(const int* __restrict__ ei,
    int* __restrict__ cur, int* __restrict__ esrc8)
{
    int e = blockIdx.x * 256 + threadIdx.x;
    int t = blockIdx.y;
    if (e >= EE) return;
    const int* eit = ei + (size_t)t * 2 * EE;
    int src = eit[e], dst = eit[EE + e];
    int pos = atomicAdd(&cur[t * NN + dst], 1);
    esrc8[(size_t)t * EE + pos] = src;
}

// ---- per-node GAT, one WAVE per node; segment canonicalized (sorted by src)
//      in LDS so the fp accumulation order is deterministic across calls -----
__global__ __launch_bounds__(256) void k_gat_node(const int* __restrict__ rowptr,
    const int* __restrict__ deg, const int* __restrict__ esrc8,
    const float* __restrict__ p1, const float* __restrict__ p2,
    const unsigned* __restrict__ h32, const unsigned* __restrict__ x32,
    const float* __restrict__ g, const float* __restrict__ b,
    unsigned* __restrict__ seq32)
{
    __shared__ int sseg [4][MAXD];
    __shared__ int sseg2[4][MAXD];
    int lane = threadIdx.x & 63;
    int nloc = threadIdx.x >> 6;
    int n = blockIdx.x * 4 + nloc;
    int j0 = lane * 2;
    int head = lane >> 3;                       // (2*lane)>>4
    float p2h = p2[(size_t)n * NSH + head];
    unsigned xv = x32[(size_t)n * 64 + lane];
    float xv0 = b2f((unsigned short)xv), xv1 = b2f((unsigned short)(xv >> 16));
    float gj0 = g[j0], gj1 = g[j0 + 1], bj0 = b[j0], bj1 = b[j0 + 1];
    float dv = __expf((float)j0 * (-9.210340371976184f / 128.f));

    for (int t = 0; t < TT; ++t) {
        const int* es = esrc8 + (size_t)t * EE;
        int start = rowptr[t * NN + n], dg = deg[t * NN + n];

        // canonicalize segment order: sort by src (ties by staged index —
        // equal srcs contribute identical values, so order among them is
        // irrelevant to the fp result). All intra-wave; no block barrier.
        const int* lst;
        if (dg <= MAXD) {
            int* sg  = sseg[nloc];
            int* sg2 = sseg2[nloc];
            for (int i = lane; i < dg; i += 64) sg[i] = es[start + i];
            for (int i = lane; i < dg; i += 64) {
                int si = sg[i];
                int r = 0;
                for (int jj = 0; jj < dg; ++jj) {
                    int sj = sg[jj];
                    r += (sj < si) || (sj == si && jj < i);
                }
                sg2[r] = si;
            }
            lst = sg2;
        } else {
            lst = es + start;   // fallback (never hit for this input)
        }

        float z = 0.f, a0 = 0.f, a1 = 0.f;
        int ee = 0;
        for (; ee + 1 < dg; ee += 2) {
            int s0 = lst[ee], s1 = lst[ee + 1];
            float v0 = p1[(size_t)s0 * NSH + head] + p2h;
            float v1 = p1[(size_t)s1 * NSH + head] + p2h;
            v0 = fmaxf(v0, 0.2f * v0);
            v1 = fmaxf(v1, 0.2f * v1);
            float e0 = __expf(v0), e1 = __expf(v1);
            unsigned hv0 = h32[(size_t)s0 * 64 + lane];
            unsigned hv1 = h32[(size_t)s1 * 64 + lane];
            z += e0 + e1;
            a0 = fmaf(e0, b2f((unsigned short)hv0), a0);
            a1 = fmaf(e0, b2f((unsigned short)(hv0 >> 16)), a1);
            a0 = fmaf(e1, b2f((unsigned short)hv1), a0);
            a1 = fmaf(e1, b2f((unsigned short)(hv1 >> 16)), a1);
        }
        if (ee < dg) {
            int s0 = lst[ee];
            float v0 = p1[(size_t)s0 * NSH + head] + p2h;
            v0 = fmaxf(v0, 0.2f * v0);
            float e0 = __expf(v0);
            unsigned hv0 = h32[(size_t)s0 * 64 + lane];
            z += e0;
            a0 = fmaf(e0, b2f((unsigned short)hv0), a0);
            a1 = fmaf(e0, b2f((unsigned short)(hv0 >> 16)), a1);
        }
        float rz = dg > 0 ? 1.f / z : 0.f;

        float v0 = a0 * rz + xv0, v1 = a1 * rz + xv1;
        float s1v = v0 + v1, s2v = v0 * v0 + v1 * v1;
        #pragma unroll
        for (int off = 32; off; off >>= 1) {
            s1v += __shfl_xor(s1v, off);
            s2v += __shfl_xor(s2v, off);
        }
        float mu  = s1v * (1.f / HH);
        float var = s2v * (1.f / HH) - mu * mu;
        float rstd = rsqrtf(var + 1e-5f);
        float y0 = (v0 - mu) * rstd * gj0 + bj0;
        float y1 = (v1 - mu) * rstd * gj1 + bj1;
        y0 = y0 > 0.f ? y0 : (__expf(y0) - 1.f);
        y1 = y1 > 0.f ? y1 : (__expf(y1) - 1.f);
        float ang = (float)t * dv;
        y0 += sinf(ang);
        y1 += cosf(ang);
        seq32[((size_t)t * NN + n) * 64 + lane] =
            (unsigned)f2b(y0) | ((unsigned)f2b(y1) << 16);
    }
}

// ---- fused temporal block ----------------------------------------------------
#define Q_OFF 65536
#define O_OFF 69760
#define LDS_SZ 74112

__global__ __launch_bounds__(256, 2) void k_temporal(
    const unsigned short* __restrict__ seq, const unsigned short* __restrict__ wkv,
    const unsigned short* __restrict__ wq, const unsigned short* __restrict__ wo,
    const float* __restrict__ bqkv, const float* __restrict__ bo,
    const float* __restrict__ g2, const float* __restrict__ b2,
    const float* __restrict__ Wc, const float* __restrict__ bc,
    float* __restrict__ out)
{
    __shared__ __align__(16) char lds[LDS_SZ];
    unsigned short* Q_s = (unsigned short*)(lds + Q_OFF);
    unsigned short* o_s = (unsigned short*)(lds + O_OFF);
    float*          y_s = (float*)lds;

    int tid = threadIdx.x;
    int n0 = blockIdx.x * 16;
    int wid = tid >> 6, lane = tid & 63, lm = lane & 15, kg = lane >> 4;

    for (int w = tid; w < 2048; w += 256) {
        int r = w >> 4, u = w & 15;
        int t = r & 7, ln = r >> 3;
        int byte = (r * 256 + u * 16) ^ ((r & 7) << 4);
        *(short8*)(lds + byte) = *(const short8*)(seq + ((size_t)t * NN + n0 + ln) * HH + u * 8);
    }
    __syncthreads();

    short8 bf[4][4];
    #pragma unroll
    for (int ntl = 0; ntl < 4; ++ntl) {
        int T = wid * 4 + ntl;
        #pragma unroll
        for (int ks = 0; ks < 4; ++ks)
            bf[ntl][ks] = *(const short8*)(wkv + (size_t)(T * 16 + lm) * HH + ks * 32 + kg * 8);
    }
    f32x4 acc[8][4];
    #pragma unroll
    for (int mt = 0; mt < 8; ++mt)
        #pragma unroll
        for (int ntl = 0; ntl < 4; ++ntl)
            acc[mt][ntl] = (f32x4){0.f, 0.f, 0.f, 0.f};
    #pragma unroll
    for (int mt = 0; mt < 8; ++mt) {
        int arow = mt * 16 + lm;
        int ab = arow * 256, swz = (arow & 7) << 4;
        short8 af[4];
        #pragma unroll
        for (int ks = 0; ks < 4; ++ks)
            af[ks] = *(short8*)(lds + ((ab + ks * 64 + kg * 16) ^ swz));
        #pragma unroll
        for (int ntl = 0; ntl < 4; ++ntl)
            #pragma unroll
            for (int ks = 0; ks < 4; ++ks)
                acc[mt][ntl] = __builtin_amdgcn_mfma_f32_16x16x32_bf16(
                    af[ks], bf[ntl][ks], acc[mt][ntl], 0, 0, 0);
    }
    f32x4 qacc[2];
    qacc[0] = (f32x4){0.f,0.f,0.f,0.f}; qacc[1] = (f32x4){0.f,0.f,0.f,0.f};
    {
        int arow = lm * 8 + 7;
        int ab = arow * 256, swz = 7 << 4;
        short8 afq[4];
        #pragma unroll
        for (int ks = 0; ks < 4; ++ks)
            afq[ks] = *(short8*)(lds + ((ab + ks * 64 + kg * 16) ^ swz));
        #pragma unroll
        for (int q2 = 0; q2 < 2; ++q2) {
            int Tq = wid * 2 + q2;
            #pragma unroll
            for (int ks = 0; ks < 4; ++ks)
                qacc[q2] = __builtin_amdgcn_mfma_f32_16x16x32_bf16(
                    afq[ks], *(const short8*)(wq + (size_t)(Tq * 16 + lm) * HH + ks * 32 + kg * 8),
                    qacc[q2], 0, 0, 0);
        }
    }
    __syncthreads();

    #pragma unroll
    for (int mt = 0; mt < 8; ++mt)
        #pragma unroll
        for (int ntl = 0; ntl < 4; ++ntl) {
            int kvidx = (wid * 4 + ntl) * 16 + lm;
            int r0 = mt * 16 + kg * 4;
            int byte = (kvidx * 256 + r0 * 2) ^ ((kvidx & 7) << 4);
            unsigned p01 = (unsigned)f2b(acc[mt][ntl][0]) | ((unsigned)f2b(acc[mt][ntl][1]) << 16);
            unsigned p23 = (unsigned)f2b(acc[mt][ntl][2]) | ((unsigned)f2b(acc[mt][ntl][3]) << 16);
            *(unsigned*)(lds + byte)     = p01;
            *(unsigned*)(lds + byte + 4) = p23;
        }
    #pragma unroll
    for (int q2 = 0; q2 < 2; ++q2) {
        int qcol = (wid * 2 + q2) * 16 + lm;
        #pragma unroll
        for (int rg = 0; rg < 4; ++rg)
            Q_s[(kg * 4 + rg) * 132 + qcol] = f2b(qacc[q2][rg]);
    }
    __syncthreads();

    int sub = tid >> 7, j = tid & 127, hh = j >> 5, d = j & 31;
    float bq = bqkv[hh * 96 + d], bk = bqkv[hh * 96 + 32 + d], bv = bqkv[hh * 96 + 64 + d];
    int kidx = hh * 64 + d, vidx = hh * 64 + 32 + d;
    int kswz = (kidx & 7) << 4, vswz = (vidx & 7) << 4;
    #pragma unroll
    for (int it = 0; it < 8; ++it) {
        int ln = it * 2 + sub;
        int kb = (kidx * 256 + ln * 16) ^ kswz;
        int vb = (vidx * 256 + ln * 16) ^ vswz;
        short4v k01 = *(short4v*)(lds + kb);
        short4v k23 = *(short4v*)(lds + kb + 8);
        short4v v01 = *(short4v*)(lds + vb);
        short4v v23 = *(short4v*)(lds + vb + 8);
        float qv = b2f(Q_s[ln * 132 + j]) + bq;
        float kk[8] = {b2f((unsigned short)k01[0]), b2f((unsigned short)k01[1]),
                       b2f((unsigned short)k01[2]), b2f((unsigned short)k01[3]),
                       b2f((unsigned short)k23[0]), b2f((unsigned short)k23[1]),
                       b2f((unsigned short)k23[2]), b2f((unsigned short)k23[3])};
        float vvv[8] = {b2f((unsigned short)v01[0]), b2f((unsigned short)v01[1]),
                        b2f((unsigned short)v01[2]), b2f((unsigned short)v01[3]),
                        b2f((unsigned short)v23[0]), b2f((unsigned short)v23[1]),
                        b2f((unsigned short)v23[2]), b2f((unsigned short)v23[3])};
        float sc[8];
        #pragma unroll
        for (int t = 0; t < 8; ++t) {
            float p = qv * (kk[t] + bk);
            #pragma unroll
            for (int off = 16; off; off >>= 1) p += __shfl_xor(p, off);
            sc[t] = p * 0.17677669529663689f;
        }
        float mx = sc[0];
        #pragma unroll
        for (int t = 1; t < 8; ++t) mx = fmaxf(mx, sc[t]);
        float se = 0.f;
        #pragma unroll
        for (int t = 0; t < 8; ++t) { sc[t] = __expf(sc[t] - mx); se += sc[t]; }
        float inv = 1.f / se, ov = 0.f;
        #pragma unroll
        for (int t = 0; t < 8; ++t) ov = fmaf(sc[t] * inv, vvv[t] + bv, ov);
        o_s[ln * 136 + j] = f2b(ov);
    }
    __syncthreads();

    short8 af2[4];
    #pragma unroll
    for (int ks = 0; ks < 4; ++ks)
        af2[ks] = *(short8*)((char*)o_s + lm * 272 + ks * 64 + kg * 16);
    f32x4 yac[2];
    yac[0] = (f32x4){0.f,0.f,0.f,0.f}; yac[1] = (f32x4){0.f,0.f,0.f,0.f};
    #pragma unroll
    for (int q2 = 0; q2 < 2; ++q2) {
        int col0 = (wid * 2 + q2) * 16;
        #pragma unroll
        for (int ks = 0; ks < 4; ++ks)
            yac[q2] = __builtin_amdgcn_mfma_f32_16x16x32_bf16(
                af2[ks], *(const short8*)(wo + (size_t)(col0 + lm) * HH + ks * 32 + kg * 8),
                yac[q2], 0, 0, 0);
    }
    #pragma unroll
    for (int q2 = 0; q2 < 2; ++q2) {
        int col0 = (wid * 2 + q2) * 16;
        #pragma unroll
        for (int rg = 0; rg < 4; ++rg)
            y_s[(kg * 4 + rg) * 132 + col0 + lm] = yac[q2][rg];
    }
    __syncthreads();

    #pragma unroll
    for (int it2 = 0; it2 < 4; ++it2) {
        int row = it2 * 4 + wid;
        int j0 = 2 * lane;
        float2 yv  = *(float2*)(y_s + row * 132 + j0);
        float2 bov = *(const float2*)(bo + j0);
        unsigned s7 = *(const unsigned*)(seq + ((size_t)7 * NN + n0 + row) * HH + j0);
        float y0 = yv.x + bov.x + b2f((unsigned short)s7);
        float y1 = yv.y + bov.y + b2f((unsigned short)(s7 >> 16));
        float s1 = y0 + y1, s2 = y0 * y0 + y1 * y1;
        #pragma unroll
        for (int off = 32; off; off >>= 1) { s1 += __shfl_xor(s1, off); s2 += __shfl_xor(s2, off); }
        float mu  = s1 * (1.f / HH);
        float var = s2 * (1.f / HH) - mu * mu;
        float rstd = rsqrtf(var + 1e-5f);
        float2 gv  = *(const float2*)(g2 + j0);
        float2 bvv = *(const float2*)(b2 + j0);
        float f0 = (y0 - mu) * rstd * gv.x + bvv.x;
        float f1 = (y1 - mu) * rstd * gv.y + bvv.y;
        f0 = f0 > 0.f ? f0 : (__expf(f0) - 1.f);
        f1 = f1 > 0.f ? f1 : (__expf(f1) - 1.f);
        y_s[row * 132 + j0]     = f0;
        y_s[row * 132 + j0 + 1] = f1;
    }
    __syncthreads();

    if (tid < 160) {
        int ln = tid / 10, c = tid - ln * 10;
        float a = bc[c];
        const float* wc = Wc + c * HH;
        #pragma unroll 8
        for (int i = 0; i < HH; ++i) a = fmaf(wc[i], y_s[ln * 132 + i], a);
        out[(size_t)(n0 + ln) * CC + c] = a;
    }
}

extern "C" void kernel_launch(void* const* d_in, const int* in_sizes, int n_in,
                              void* d_out, int out_size, void* d_ws, size_t ws_size,
                              hipStream_t stream)
{
    const float* xo   = (const float*)d_in[0];
    const int*   ei   = (const int*)d_in[1];
    const float* Wp   = (const float*)d_in[3];
    const float* bp   = (const float*)d_in[4];
    const float* Wg   = (const float*)d_in[5];
    const float* a    = (const float*)d_in[6];
    const float* g1   = (const float*)d_in[7];
    const float* b1   = (const float*)d_in[8];
    const float* Wqkv = (const float*)d_in[9];
    const float* bqkv = (const float*)d_in[10];
    const float* Wo   = (const float*)d_in[11];
    const float* bo   = (const float*)d_in[12];
    const float* g2   = (const float*)d_in[13];
    const float* b2   = (const float*)d_in[14];
    const float* Wc   = (const float*)d_in[15];
    const float* bc   = (const float*)d_in[16];
    float* out = (float*)d_out;

    // workspace layout (byte offsets, 16B aligned)
    char* W = (char*)d_ws;
    unsigned short* xb     = (unsigned short*)(W + 0);        // 12,800,000
    float*          p1     = (float*)(W + 12800000);          //  1,600,000
    float*          p2     = (float*)(W + 14400000);          //  1,600,000
    unsigned short* h      = (unsigned short*)(W + 16000000); // 12,800,000
    unsigned short* seq    = (unsigned short*)(W + 28800000); // 102,400,000
    int*            deg    = (int*)(W + 131200000);           //  1,600,000
    int*            rowptr = (int*)(W + 132800000);           //  1,600,000
    int*            cur    = (int*)(W + 134400000);           //  1,600,000
    int*            esrc8  = (int*)(W + 136000000);           // 12,800,000 (T*E)
    unsigned short* wkv    = (unsigned short*)(W + 148800000);//     65,536
    unsigned short* wq     = (unsigned short*)(W + 148865536);//     32,768
    unsigned short* wo     = (unsigned short*)(W + 148898304);//     32,768
    unsigned short* wp_b   = (unsigned short*)(W + 148931072);//     16,384
    unsigned short* wg_b   = (unsigned short*)(W + 148947456);//     32,768
    int*            csum   = (int*)(W + 148980224);           //      1,568
    if (ws_size < (size_t)148981808) return;

    hipMemsetAsync(deg, 0, (size_t)TT * NN * sizeof(int), stream);

    k_wcvt   <<<352, 256, 0, stream>>>(Wqkv, Wo, Wp, Wg, wkv, wq, wo, wp_b, wg_b);
    k_projh  <<<(NN + 63) / 64, 256, 0, stream>>>(xo, wp_b, bp, wg_b, a, xb, h, p1, p2);
    k_deg    <<<dim3((EE + 255) / 256, TT), 256, 0, stream>>>(ei, deg);
    k_scan1  <<<dim3(NCH, TT), 256, 0, stream>>>(deg, csum);
    k_scan2  <<<1, 64, 0, stream>>>(csum);
    k_scan3  <<<dim3(NCH, TT), 256, 0, stream>>>(deg, csum, rowptr, cur);
    k_scatter<<<dim3((EE + 255) / 256, TT), 256, 0, stream>>>(ei, cur, esrc8);
    k_gat_node<<<NN / 4, 256, 0, stream>>>(rowptr, deg, esrc8, p1, p2,
                                           (const unsigned*)h, (const unsigned*)xb,
                                           g1, b1, (unsigned*)seq);
    k_temporal<<<NN / 16, 256, 0, stream>>>(seq, wkv, wq, wo, bqkv, bo,
                                            g2, b2, Wc, bc, out);
}

// Round 12
// 758.968 us; speedup vs baseline: 1.1888x; 1.1888x over previous
//
#include <hip/hip_runtime.h>
#include <hip/hip_bf16.h>
#include <math.h>

#define NN   50000
#define INF_ 64
#define HH   128
#define NSH  8
#define TT   8
#define EE   400000
#define CC   10

typedef __attribute__((ext_vector_type(8))) short short8;
typedef __attribute__((ext_vector_type(4))) short short4v;
typedef __attribute__((ext_vector_type(4))) float f32x4;

__device__ __forceinline__ float b2f(unsigned short u){
    unsigned v = ((unsigned)u) << 16; float f; __builtin_memcpy(&f, &v, 4); return f;
}
__device__ __forceinline__ unsigned short f2b(float f){
    unsigned x; __builtin_memcpy(&x, &f, 4);
    x += 0x7fffu + ((x >> 16) & 1u);
    return (unsigned short)(x >> 16);
}

// ---- weight preconvert ------------------------------------------------------
__global__ __launch_bounds__(256) void k_wcvt(const float* __restrict__ Wqkv,
    const float* __restrict__ Wo, const float* __restrict__ Wp,
    const float* __restrict__ Wg, unsigned short* __restrict__ wkv,
    unsigned short* __restrict__ wq, unsigned short* __restrict__ wo_,
    unsigned short* __restrict__ wp_, unsigned short* __restrict__ wg_)
{
    int idx = blockIdx.x * 256 + threadIdx.x;
    if (idx < 32768) {                                  // K,V rows
        int r = idx >> 7, c = idx & 127;
        int hh = r >> 6, rem = r & 63;                  // rem<32: k, else v
        wkv[idx] = f2b(Wqkv[(hh * 96 + 32 + rem) * HH + c]);
    } else if (idx < 49152) {                           // Q rows
        int i2 = idx - 32768;
        int r = i2 >> 7, c = i2 & 127;
        int hh = r >> 5, dd = r & 31;
        wq[i2] = f2b(Wqkv[(hh * 96 + dd) * HH + c]);
    } else if (idx < 65536) {
        int i2 = idx - 49152;
        wo_[i2] = f2b(Wo[i2]);
    } else if (idx < 73728) {
        int i2 = idx - 65536;
        wp_[i2] = f2b(Wp[i2]);
    } else {                                            // < 90112
        int i2 = idx - 73728;
        wg_[i2] = f2b(Wg[i2]);
    }
}

// ---- fused: x = elu(x0@Wp.T+bp) (bf16); h = x@Wg.T (bf16); p1,p2 -----------
__global__ __launch_bounds__(256) void k_projh(const float* __restrict__ xo,
    const unsigned short* __restrict__ wp, const float* __restrict__ bp,
    const unsigned short* __restrict__ wg, const float* __restrict__ a,
    unsigned short* __restrict__ xb, unsigned short* __restrict__ h,
    float* __restrict__ p1, float* __restrict__ p2)
{
    __shared__ __align__(16) char lds[40960];
    int tid = threadIdx.x;
    int n0 = blockIdx.x * 64;
    int wid = tid >> 6, lane = tid & 63, lm = lane & 15, kg = lane >> 4;

    for (int w = tid; w < 512; w += 256) {
        int row = w >> 3, u = w & 7;
        int nr = n0 + row; if (nr >= NN) nr = NN - 1;
        const float4* src = (const float4*)(xo + (size_t)nr * INF_ + u * 8);
        float4 v0 = src[0], v1 = src[1];
        short8 p;
        p[0] = (short)f2b(v0.x); p[1] = (short)f2b(v0.y);
        p[2] = (short)f2b(v0.z); p[3] = (short)f2b(v0.w);
        p[4] = (short)f2b(v1.x); p[5] = (short)f2b(v1.y);
        p[6] = (short)f2b(v1.z); p[7] = (short)f2b(v1.w);
        *(short8*)(lds + ((row * 128 + u * 16) ^ ((row & 7) << 4))) = p;
    }
    __syncthreads();

    short8 bf1[2][2];
    #pragma unroll
    for (int ntl = 0; ntl < 2; ++ntl)
        #pragma unroll
        for (int ks = 0; ks < 2; ++ks)
            bf1[ntl][ks] = *(const short8*)(wp + (size_t)(wid * 32 + ntl * 16 + lm) * INF_ + ks * 32 + kg * 8);
    f32x4 acc1[4][2];
    #pragma unroll
    for (int mt = 0; mt < 4; ++mt)
        #pragma unroll
        for (int ntl = 0; ntl < 2; ++ntl)
            acc1[mt][ntl] = (f32x4){0.f, 0.f, 0.f, 0.f};
    #pragma unroll
    for (int mt = 0; mt < 4; ++mt) {
        int row = mt * 16 + lm, swz = (row & 7) << 4, ab = row * 128;
        short8 af[2];
        #pragma unroll
        for (int ks = 0; ks < 2; ++ks)
            af[ks] = *(short8*)(lds + ((ab + ks * 64 + kg * 16) ^ swz));
        #pragma unroll
        for (int ntl = 0; ntl < 2; ++ntl)
            #pragma unroll
            for (int ks = 0; ks < 2; ++ks)
                acc1[mt][ntl] = __builtin_amdgcn_mfma_f32_16x16x32_bf16(
                    af[ks], bf1[ntl][ks], acc1[mt][ntl], 0, 0, 0);
    }

    #pragma unroll
    for (int mt = 0; mt < 4; ++mt)
        #pragma unroll
        for (int ntl = 0; ntl < 2; ++ntl) {
            int j = wid * 32 + ntl * 16 + lm;
            float bpj = bp[j];
            #pragma unroll
            for (int r = 0; r < 4; ++r) {
                int rowl = mt * 16 + kg * 4 + r;
                float v = acc1[mt][ntl][r] + bpj;
                v = v > 0.f ? v : (__expf(v) - 1.f);
                int node = n0 + rowl;
                unsigned short vb = f2b(v);
                if (node < NN) xb[(size_t)node * HH + j] = vb;
                *(unsigned short*)(lds + 8192 + ((rowl * 256 + j * 2) ^ ((rowl & 7) << 4))) = vb;
            }
        }
    __syncthreads();

    short8 bf2[2][4];
    #pragma unroll
    for (int ntl = 0; ntl < 2; ++ntl)
        #pragma unroll
        for (int ks = 0; ks < 4; ++ks)
            bf2[ntl][ks] = *(const short8*)(wg + (size_t)(wid * 32 + ntl * 16 + lm) * HH + ks * 32 + kg * 8);
    f32x4 acc2[4][2];
    #pragma unroll
    for (int mt = 0; mt < 4; ++mt)
        #pragma unroll
        for (int ntl = 0; ntl < 2; ++ntl)
            acc2[mt][ntl] = (f32x4){0.f, 0.f, 0.f, 0.f};
    #pragma unroll
    for (int mt = 0; mt < 4; ++mt) {
        int row = mt * 16 + lm, swz = (row & 7) << 4, ab = row * 256;
        short8 af[4];
        #pragma unroll
        for (int ks = 0; ks < 4; ++ks)
            af[ks] = *(short8*)(lds + 8192 + ((ab + ks * 64 + kg * 16) ^ swz));
        #pragma unroll
        for (int ntl = 0; ntl < 2; ++ntl)
            #pragma unroll
            for (int ks = 0; ks < 4; ++ks)
                acc2[mt][ntl] = __builtin_amdgcn_mfma_f32_16x16x32_bf16(
                    af[ks], bf2[ntl][ks], acc2[mt][ntl], 0, 0, 0);
    }

    float a1v = a[lm], a2v = a[16 + lm];
    #pragma unroll
    for (int mt = 0; mt < 4; ++mt)
        #pragma unroll
        for (int ntl = 0; ntl < 2; ++ntl) {
            int head = wid * 2 + ntl;
            int j = wid * 32 + ntl * 16 + lm;
            float c1r[4], c2r[4];
            #pragma unroll
            for (int r = 0; r < 4; ++r) {
                float hv = acc2[mt][ntl][r];
                int node = n0 + mt * 16 + kg * 4 + r;
                if (node < NN) h[(size_t)node * HH + j] = f2b(hv);
                c1r[r] = hv * a1v;
                c2r[r] = hv * a2v;
            }
            #pragma unroll
            for (int off = 1; off < 16; off <<= 1)
                #pragma unroll
                for (int r = 0; r < 4; ++r) {
                    c1r[r] += __shfl_xor(c1r[r], off);
                    c2r[r] += __shfl_xor(c2r[r], off);
                }
            if (lm == 0) {
                #pragma unroll
                for (int r = 0; r < 4; ++r) {
                    int node = n0 + mt * 16 + kg * 4 + r;
                    if (node < NN) {
                        p1[(size_t)node * NSH + head] = c1r[r];
                        p2[(size_t)node * NSH + head] = c2r[r];
                    }
                }
            }
        }
}

// ---- degree histogram over all snapshots -----------------------------------
__global__ __launch_bounds__(256) void k_deg(const int* __restrict__ ei, int* __restrict__ deg)
{
    int e = blockIdx.x * 256 + threadIdx.x;
    int t = blockIdx.y;
    if (e >= EE) return;
    int dst = ei[(size_t)t * 2 * EE + EE + e];
    atomicAdd(&deg[t * NN + dst], 1);
}

// ---- hierarchical scan: chunk sums -> chunk offsets -> in-chunk scan --------
#define NCH 49   // ceil(50000/1024)

__global__ __launch_bounds__(256) void k_scan1(const int* __restrict__ deg,
    int* __restrict__ csum)
{
    int t = blockIdx.y, c = blockIdx.x, tid = threadIdx.x;
    int base = c * 1024;
    int s = 0;
    #pragma unroll
    for (int k = 0; k < 4; ++k) {
        int i = base + k * 256 + tid;
        if (i < NN) s += deg[t * NN + i];
    }
    #pragma unroll
    for (int off = 32; off; off >>= 1) s += __shfl_xor(s, off);
    __shared__ int sm[4];
    if ((tid & 63) == 0) sm[tid >> 6] = s;
    __syncthreads();
    if (tid == 0) csum[t * NCH + c] = sm[0] + sm[1] + sm[2] + sm[3];
}

__global__ __launch_bounds__(64) void k_scan2(int* __restrict__ csum)
{
    int t = threadIdx.x;
    if (t >= TT) return;
    int run = 0;
    for (int c = 0; c < NCH; ++c) {
        int v = csum[t * NCH + c];
        csum[t * NCH + c] = run;
        run += v;
    }
}

__global__ __launch_bounds__(256) void k_scan3(const int* __restrict__ deg,
    const int* __restrict__ csum, int* __restrict__ rowptr, int* __restrict__ cur)
{
    int t = blockIdx.y, c = blockIdx.x, tid = threadIdx.x;
    int i0 = c * 1024 + tid * 4;
    int d[4];
    int s = 0;
    #pragma unroll
    for (int k = 0; k < 4; ++k) {
        d[k] = (i0 + k < NN) ? deg[t * NN + i0 + k] : 0;
        s += d[k];
    }
    __shared__ int sm[256];
    sm[tid] = s;
    __syncthreads();
    for (int off = 1; off < 256; off <<= 1) {
        int v = (tid >= off) ? sm[tid - off] : 0;
        __syncthreads();
        sm[tid] += v;
        __syncthreads();
    }
    int run = csum[t * NCH + c] + sm[tid] - s;
    #pragma unroll
    for (int k = 0; k < 4; ++k) {
        int i = i0 + k;
        if (i < NN) {
            rowptr[t * NN + i] = run;
            cur[t * NN + i] = run;
            run += d[k];
        }
    }
}

// ---- scatter: dst-sort edge src ids (all t); intra-segment order is
//      nondeterministic (atomic cursor) — k_gat_node canonicalizes it --------
__global__ __launch_bounds__(256) void k_scatter(const int* __restrict__ ei,
    int* __restrict__ cur, int* __restrict__ esrc8)
{
    int e = blockIdx.x * 256 + threadIdx.x;
    int t = blockIdx.y;
    if (e >= EE) return;
    const int* eit = ei + (size_t)t * 2 * EE;
    int src = eit[e], dst = eit[EE + e];
    int pos = atomicAdd(&cur[t * NN + dst], 1);
    esrc8[(size_t)t * EE + pos] = src;
}

// ---- per-node GAT, one WAVE per node; segment canonicalized by a REGISTER
//      rank-sort (one src per lane, dg<=64) so the fp accumulation order is
//      deterministic across calls. No LDS, no divergence (dg wave-uniform). --
__global__ __launch_bounds__(256) void k_gat_node(const int* __restrict__ rowptr,
    const int* __restrict__ deg, const int* __restrict__ esrc8,
    const float* __restrict__ p1, const float* __restrict__ p2,
    const unsigned* __restrict__ h32, const unsigned* __restrict__ x32,
    const float* __restrict__ g, const float* __restrict__ b,
    unsigned* __restrict__ seq32)
{
    int lane = threadIdx.x & 63;
    int n = blockIdx.x * 4 + (threadIdx.x >> 6);
    int j0 = lane * 2;
    int head = lane >> 3;                       // (2*lane)>>4
    float p2h = p2[(size_t)n * NSH + head];
    unsigned xv = x32[(size_t)n * 64 + lane];
    float xv0 = b2f((unsigned short)xv), xv1 = b2f((unsigned short)(xv >> 16));
    float gj0 = g[j0], gj1 = g[j0 + 1], bj0 = b[j0], bj1 = b[j0 + 1];
    float dv = __expf((float)j0 * (-9.210340371976184f / 128.f));

    for (int t = 0; t < TT; ++t) {
        const int* es = esrc8 + (size_t)t * EE;
        int start = rowptr[t * NN + n], dg = deg[t * NN + n];

        float z = 0.f, a0 = 0.f, a1 = 0.f;
        if (dg <= 64) {
            // canonicalize: lane i holds es[start+i]; rank by (src, lane);
            // ties have identical values so tie order can't change the result.
            int si = (lane < dg) ? es[start + lane] : 0x7fffffff;
            int cnt = 0;
            for (int jj = 0; jj < dg; ++jj) {
                int sj = __shfl(si, jj);
                cnt += (sj < si) || (sj == si && jj < lane);
            }
            int r = (lane < dg) ? cnt : lane;           // unique ranks
            int sorted = __builtin_amdgcn_ds_permute(r << 2, si);

            int ee = 0;
            for (; ee + 1 < dg; ee += 2) {
                int s0 = __shfl(sorted, ee), s1 = __shfl(sorted, ee + 1);
                float v0 = p1[(size_t)s0 * NSH + head] + p2h;
                float v1 = p1[(size_t)s1 * NSH + head] + p2h;
                v0 = fmaxf(v0, 0.2f * v0);
                v1 = fmaxf(v1, 0.2f * v1);
                float e0 = __expf(v0), e1 = __expf(v1);
                unsigned hv0 = h32[(size_t)s0 * 64 + lane];
                unsigned hv1 = h32[(size_t)s1 * 64 + lane];
                z += e0 + e1;
                a0 = fmaf(e0, b2f((unsigned short)hv0), a0);
                a1 = fmaf(e0, b2f((unsigned short)(hv0 >> 16)), a1);
                a0 = fmaf(e1, b2f((unsigned short)hv1), a0);
                a1 = fmaf(e1, b2f((unsigned short)(hv1 >> 16)), a1);
            }
            if (ee < dg) {
                int s0 = __shfl(sorted, ee);
                float v0 = p1[(size_t)s0 * NSH + head] + p2h;
                v0 = fmaxf(v0, 0.2f * v0);
                float e0 = __expf(v0);
                unsigned hv0 = h32[(size_t)s0 * 64 + lane];
                z += e0;
                a0 = fmaf(e0, b2f((unsigned short)hv0), a0);
                a1 = fmaf(e0, b2f((unsigned short)(hv0 >> 16)), a1);
            }
        } else {
            // unreachable for this input (deg ~ Poisson(8)); unsorted fallback
            for (int ee = 0; ee < dg; ++ee) {
                int s0 = es[start + ee];
                float v0 = p1[(size_t)s0 * NSH + head] + p2h;
                v0 = fmaxf(v0, 0.2f * v0);
                float e0 = __expf(v0);
                unsigned hv0 = h32[(size_t)s0 * 64 + lane];
                z += e0;
                a0 = fmaf(e0, b2f((unsigned short)hv0), a0);
                a1 = fmaf(e0, b2f((unsigned short)(hv0 >> 16)), a1);
            }
        }
        float rz = dg > 0 ? 1.f / z : 0.f;

        float v0 = a0 * rz + xv0, v1 = a1 * rz + xv1;
        float s1v = v0 + v1, s2v = v0 * v0 + v1 * v1;
        #pragma unroll
        for (int off = 32; off; off >>= 1) {
            s1v += __shfl_xor(s1v, off);
            s2v += __shfl_xor(s2v, off);
        }
        float mu  = s1v * (1.f / HH);
        float var = s2v * (1.f / HH) - mu * mu;
        float rstd = rsqrtf(var + 1e-5f);
        float y0 = (v0 - mu) * rstd * gj0 + bj0;
        float y1 = (v1 - mu) * rstd * gj1 + bj1;
        y0 = y0 > 0.f ? y0 : (__expf(y0) - 1.f);
        y1 = y1 > 0.f ? y1 : (__expf(y1) - 1.f);
        float ang = (float)t * dv;
        y0 += sinf(ang);
        y1 += cosf(ang);
        seq32[((size_t)t * NN + n) * 64 + lane] =
            (unsigned)f2b(y0) | ((unsigned)f2b(y1) << 16);
    }
}

// ---- fused temporal block ----------------------------------------------------
#define Q_OFF 65536
#define O_OFF 69760
#define LDS_SZ 74112

__global__ __launch_bounds__(256, 2) void k_temporal(
    const unsigned short* __restrict__ seq, const unsigned short* __restrict__ wkv,
    const unsigned short* __restrict__ wq, const unsigned short* __restrict__ wo,
    const float* __restrict__ bqkv, const float* __restrict__ bo,
    const float* __restrict__ g2, const float* __restrict__ b2,
    const float* __restrict__ Wc, const float* __restrict__ bc,
    float* __restrict__ out)
{
    __shared__ __align__(16) char lds[LDS_SZ];
    unsigned short* Q_s = (unsigned short*)(lds + Q_OFF);
    unsigned short* o_s = (unsigned short*)(lds + O_OFF);
    float*          y_s = (float*)lds;

    int tid = threadIdx.x;
    int n0 = blockIdx.x * 16;
    int wid = tid >> 6, lane = tid & 63, lm = lane & 15, kg = lane >> 4;

    for (int w = tid; w < 2048; w += 256) {
        int r = w >> 4, u = w & 15;
        int t = r & 7, ln = r >> 3;
        int byte = (r * 256 + u * 16) ^ ((r & 7) << 4);
        *(short8*)(lds + byte) = *(const short8*)(seq + ((size_t)t * NN + n0 + ln) * HH + u * 8);
    }
    __syncthreads();

    short8 bf[4][4];
    #pragma unroll
    for (int ntl = 0; ntl < 4; ++ntl) {
        int T = wid * 4 + ntl;
        #pragma unroll
        for (int ks = 0; ks < 4; ++ks)
            bf[ntl][ks] = *(const short8*)(wkv + (size_t)(T * 16 + lm) * HH + ks * 32 + kg * 8);
    }
    f32x4 acc[8][4];
    #pragma unroll
    for (int mt = 0; mt < 8; ++mt)
        #pragma unroll
        for (int ntl = 0; ntl < 4; ++ntl)
            acc[mt][ntl] = (f32x4){0.f, 0.f, 0.f, 0.f};
    #pragma unroll
    for (int mt = 0; mt < 8; ++mt) {
        int arow = mt * 16 + lm;
        int ab = arow * 256, swz = (arow & 7) << 4;
        short8 af[4];
        #pragma unroll
        for (int ks = 0; ks < 4; ++ks)
            af[ks] = *(short8*)(lds + ((ab + ks * 64 + kg * 16) ^ swz));
        #pragma unroll
        for (int ntl = 0; ntl < 4; ++ntl)
            #pragma unroll
            for (int ks = 0; ks < 4; ++ks)
                acc[mt][ntl] = __builtin_amdgcn_mfma_f32_16x16x32_bf16(
                    af[ks], bf[ntl][ks], acc[mt][ntl], 0, 0, 0);
    }
    f32x4 qacc[2];
    qacc[0] = (f32x4){0.f,0.f,0.f,0.f}; qacc[1] = (f32x4){0.f,0.f,0.f,0.f};
    {
        int arow = lm * 8 + 7;
        int ab = arow * 256, swz = 7 << 4;
        short8 afq[4];
        #pragma unroll
        for (int ks = 0; ks < 4; ++ks)
            afq[ks] = *(short8*)(lds + ((ab + ks * 64 + kg * 16) ^ swz));
        #pragma unroll
        for (int q2 = 0; q2 < 2; ++q2) {
            int Tq = wid * 2 + q2;
            #pragma unroll
            for (int ks = 0; ks < 4; ++ks)
                qacc[q2] = __builtin_amdgcn_mfma_f32_16x16x32_bf16(
                    afq[ks], *(const short8*)(wq + (size_t)(Tq * 16 + lm) * HH + ks * 32 + kg * 8),
                    qacc[q2], 0, 0, 0);
        }
    }
    __syncthreads();

    #pragma unroll
    for (int mt = 0; mt < 8; ++mt)
        #pragma unroll
        for (int ntl = 0; ntl < 4; ++ntl) {
            int kvidx = (wid * 4 + ntl) * 16 + lm;
            int r0 = mt * 16 + kg * 4;
            int byte = (kvidx * 256 + r0 * 2) ^ ((kvidx & 7) << 4);
            unsigned p01 = (unsigned)f2b(acc[mt][ntl][0]) | ((unsigned)f2b(acc[mt][ntl][1]) << 16);
            unsigned p23 = (unsigned)f2b(acc[mt][ntl][2]) | ((unsigned)f2b(acc[mt][ntl][3]) << 16);
            *(unsigned*)(lds + byte)     = p01;
            *(unsigned*)(lds + byte + 4) = p23;
        }
    #pragma unroll
    for (int q2 = 0; q2 < 2; ++q2) {
        int qcol = (wid * 2 + q2) * 16 + lm;
        #pragma unroll
        for (int rg = 0; rg < 4; ++rg)
            Q_s[(kg * 4 + rg) * 132 + qcol] = f2b(qacc[q2][rg]);
    }
    __syncthreads();

    int sub = tid >> 7, j = tid & 127, hh = j >> 5, d = j & 31;
    float bq = bqkv[hh * 96 + d], bk = bqkv[hh * 96 + 32 + d], bv = bqkv[hh * 96 + 64 + d];
    int kidx = hh * 64 + d, vidx = hh * 64 + 32 + d;
    int kswz = (kidx & 7) << 4, vswz = (vidx & 7) << 4;
    #pragma unroll
    for (int it = 0; it < 8; ++it) {
        int ln = it * 2 + sub;
        int kb = (kidx * 256 + ln * 16) ^ kswz;
        int vb = (vidx * 256 + ln * 16) ^ vswz;
        short4v k01 = *(short4v*)(lds + kb);
        short4v k23 = *(short4v*)(lds + kb + 8);
        short4v v01 = *(short4v*)(lds + vb);
        short4v v23 = *(short4v*)(lds + vb + 8);
        float qv = b2f(Q_s[ln * 132 + j]) + bq;
        float kk[8] = {b2f((unsigned short)k01[0]), b2f((unsigned short)k01[1]),
                       b2f((unsigned short)k01[2]), b2f((unsigned short)k01[3]),
                       b2f((unsigned short)k23[0]), b2f((unsigned short)k23[1]),
                       b2f((unsigned short)k23[2]), b2f((unsigned short)k23[3])};
        float vvv[8] = {b2f((unsigned short)v01[0]), b2f((unsigned short)v01[1]),
                        b2f((unsigned short)v01[2]), b2f((unsigned short)v01[3]),
                        b2f((unsigned short)v23[0]), b2f((unsigned short)v23[1]),
                        b2f((unsigned short)v23[2]), b2f((unsigned short)v23[3])};
        float sc[8];
        #pragma unroll
        for (int t = 0; t < 8; ++t) {
            float p = qv * (kk[t] + bk);
            #pragma unroll
            for (int off = 16; off; off >>= 1) p += __shfl_xor(p, off);
            sc[t] = p * 0.17677669529663689f;
        }
        float mx = sc[0];
        #pragma unroll
        for (int t = 1; t < 8; ++t) mx = fmaxf(mx, sc[t]);
        float se = 0.f;
        #pragma unroll
        for (int t = 0; t < 8; ++t) { sc[t] = __expf(sc[t] - mx); se += sc[t]; }
        float inv = 1.f / se, ov = 0.f;
        #pragma unroll
        for (int t = 0; t < 8; ++t) ov = fmaf(sc[t] * inv, vvv[t] + bv, ov);
        o_s[ln * 136 + j] = f2b(ov);
    }
    __syncthreads();

    short8 af2[4];
    #pragma unroll
    for (int ks = 0; ks < 4; ++ks)
        af2[ks] = *(short8*)((char*)o_s + lm * 272 + ks * 64 + kg * 16);
    f32x4 yac[2];
    yac[0] = (f32x4){0.f,0.f,0.f,0.f}; yac[1] = (f32x4){0.f,0.f,0.f,0.f};
    #pragma unroll
    for (int q2 = 0; q2 < 2; ++q2) {
        int col0 = (wid * 2 + q2) * 16;
        #pragma unroll
        for (int ks = 0; ks < 4; ++ks)
            yac[q2] = __builtin_amdgcn_mfma_f32_16x16x32_bf16(
                af2[ks], *(const short8*)(wo + (size_t)(col0 + lm) * HH + ks * 32 + kg * 8),
                yac[q2], 0, 0, 0);
    }
    #pragma unroll
    for (int q2 = 0; q2 < 2; ++q2) {
        int col0 = (wid * 2 + q2) * 16;
        #pragma unroll
        for (int rg = 0; rg < 4; ++rg)
            y_s[(kg * 4 + rg) * 132 + col0 + lm] = yac[q2][rg];
    }
    __syncthreads();

    #pragma unroll
    for (int it2 = 0; it2 < 4; ++it2) {
        int row = it2 * 4 + wid;
        int j0 = 2 * lane;
        float2 yv  = *(float2*)(y_s + row * 132 + j0);
        float2 bov = *(const float2*)(bo + j0);
        unsigned s7 = *(const unsigned*)(seq + ((size_t)7 * NN + n0 + row) * HH + j0);
        float y0 = yv.x + bov.x + b2f((unsigned short)s7);
        float y1 = yv.y + bov.y + b2f((unsigned short)(s7 >> 16));
        float s1 = y0 + y1, s2 = y0 * y0 + y1 * y1;
        #pragma unroll
        for (int off = 32; off; off >>= 1) { s1 += __shfl_xor(s1, off); s2 += __shfl_xor(s2, off); }
        float mu  = s1 * (1.f / HH);
        float var = s2 * (1.f / HH) - mu * mu;
        float rstd = rsqrtf(var + 1e-5f);
        float2 gv  = *(const float2*)(g2 + j0);
        float2 bvv = *(const float2*)(b2 + j0);
        float f0 = (y0 - mu) * rstd * gv.x + bvv.x;
        float f1 = (y1 - mu) * rstd * gv.y + bvv.y;
        f0 = f0 > 0.f ? f0 : (__expf(f0) - 1.f);
        f1 = f1 > 0.f ? f1 : (__expf(f1) - 1.f);
        y_s[row * 132 + j0]     = f0;
        y_s[row * 132 + j0 + 1] = f1;
    }
    __syncthreads();

    if (tid < 160) {
        int ln = tid / 10, c = tid - ln * 10;
        float a = bc[c];
        const float* wc = Wc + c * HH;
        #pragma unroll 8
        for (int i = 0; i < HH; ++i) a = fmaf(wc[i], y_s[ln * 132 + i], a);
        out[(size_t)(n0 + ln) * CC + c] = a;
    }
}

extern "C" void kernel_launch(void* const* d_in, const int* in_sizes, int n_in,
                              void* d_out, int out_size, void* d_ws, size_t ws_size,
                              hipStream_t stream)
{
    const float* xo   = (const float*)d_in[0];
    const int*   ei   = (const int*)d_in[1];
    const float* Wp   = (const float*)d_in[3];
    const float* bp   = (const float*)d_in[4];
    const float* Wg   = (const float*)d_in[5];
    const float* a    = (const float*)d_in[6];
    const float* g1   = (const float*)d_in[7];
    const float* b1   = (const float*)d_in[8];
    const float* Wqkv = (const float*)d_in[9];
    const float* bqkv = (const float*)d_in[10];
    const float* Wo   = (const float*)d_in[11];
    const float* bo   = (const float*)d_in[12];
    const float* g2   = (const float*)d_in[13];
    const float* b2   = (const float*)d_in[14];
    const float* Wc   = (const float*)d_in[15];
    const float* bc   = (const float*)d_in[16];
    float* out = (float*)d_out;

    // workspace layout (byte offsets, 16B aligned)
    char* W = (char*)d_ws;
    unsigned short* xb     = (unsigned short*)(W + 0);        // 12,800,000
    float*          p1     = (float*)(W + 12800000);          //  1,600,000
    float*          p2     = (float*)(W + 14400000);          //  1,600,000
    unsigned short* h      = (unsigned short*)(W + 16000000); // 12,800,000
    unsigned short* seq    = (unsigned short*)(W + 28800000); // 102,400,000
    int*            deg    = (int*)(W + 131200000);           //  1,600,000
    int*            rowptr = (int*)(W + 132800000);           //  1,600,000
    int*            cur    = (int*)(W + 134400000);           //  1,600,000
    int*            esrc8  = (int*)(W + 136000000);           // 12,800,000 (T*E)
    unsigned short* wkv    = (unsigned short*)(W + 148800000);//     65,536
    unsigned short* wq     = (unsigned short*)(W + 148865536);//     32,768
    unsigned short* wo     = (unsigned short*)(W + 148898304);//     32,768
    unsigned short* wp_b   = (unsigned short*)(W + 148931072);//     16,384
    unsigned short* wg_b   = (unsigned short*)(W + 148947456);//     32,768
    int*            csum   = (int*)(W + 148980224);           //      1,568
    if (ws_size < (size_t)148981808) return;

    hipMemsetAsync(deg, 0, (size_t)TT * NN * sizeof(int), stream);

    k_wcvt   <<<352, 256, 0, stream>>>(Wqkv, Wo, Wp, Wg, wkv, wq, wo, wp_b, wg_b);
    k_projh  <<<(NN + 63) / 64, 256, 0, stream>>>(xo, wp_b, bp, wg_b, a, xb, h, p1, p2);
    k_deg    <<<dim3((EE + 255) / 256, TT), 256, 0, stream>>>(ei, deg);
    k_scan1  <<<dim3(NCH, TT), 256, 0, stream>>>(deg, csum);
    k_scan2  <<<1, 64, 0, stream>>>(csum);
    k_scan3  <<<dim3(NCH, TT), 256, 0, stream>>>(deg, csum, rowptr, cur);
    k_scatter<<<dim3((EE + 255) / 256, TT), 256, 0, stream>>>(ei, cur, esrc8);
    k_gat_node<<<NN / 4, 256, 0, stream>>>(rowptr, deg, esrc8, p1, p2,
                                           (const unsigned*)h, (const unsigned*)xb,
                                           g1, b1, (unsigned*)seq);
    k_temporal<<<NN / 16, 256, 0, stream>>>(seq, wkv, wq, wo, bqkv, bo,
                                            g2, b2, Wc, bc, out);
}